// Round 1
// baseline (705.568 us; speedup 1.0000x reference)
//
#include <hip/hip_runtime.h>
#include <hip/hip_bf16.h>
#include <math.h>

// ---------------------------------------------------------------------------
// LowRankSparseAttention on MI355X (gfx950)
// Pipeline:
//   1. cvt resid -> bf16 A (2048x1024); cvt W_V -> Wt rows 2048..4095 (native B^T)
//   2. transpose W_Q/W_K -> Wt rows 0..2047 (B^T: row n = h*32+d, contiguous K=m)
//   3. transpose W_O -> Wo_t (1024x2048 bf16, B^T: row m, contiguous K=h)
//   4. GEMM1 (bf16 MFMA 128x128): C1[2048x4096] f32 = A @ Wt^T  (Q|K|V)
//   5. rotary+bias in-place on C1 cols 0..2047
//   6. attention (f32, online softmax): Zb[2048x2048] bf16
//   7. GEMM2: out[2048x1024] f32 = Zb @ Wo_t^T
// ---------------------------------------------------------------------------

typedef short bf16x8 __attribute__((ext_vector_type(8)));
typedef float f32x4 __attribute__((ext_vector_type(4)));
typedef __hip_bfloat16 bf16;

#define AS1(p) ((const __attribute__((address_space(1))) void*)(const void*)(p))
#define AS3(p) ((__attribute__((address_space(3))) void*)(void*)(p))

static constexpr int NC1 = 4096;                     // C1 cols: Q|K|V
static constexpr float INV_SCALE = 0.17677669529663687f;  // 1/sqrt(32)

// ---- f32 -> bf16 convert (n multiple of 4) --------------------------------
__global__ void cvt_f32_bf16(const float* __restrict__ src, bf16* __restrict__ dst, int n) {
  int i = (blockIdx.x * 256 + threadIdx.x) * 4;
  if (i < n) {
    float4 v = *(const float4*)(src + i);
    dst[i + 0] = __float2bfloat16(v.x);
    dst[i + 1] = __float2bfloat16(v.y);
    dst[i + 2] = __float2bfloat16(v.z);
    dst[i + 3] = __float2bfloat16(v.w);
  }
}

// ---- W_Q/W_K (32,1024,32) -> Wt[(qk*1024 + h*32 + d)*1024 + m] bf16 -------
__global__ void transpose_wqk(const float* __restrict__ WQ, const float* __restrict__ WK,
                              bf16* __restrict__ Wt) {
  __shared__ float t[64][33];
  const int mt = blockIdx.x;   // 0..15 (m tile of 64)
  const int h  = blockIdx.y;   // 0..31
  const int qk = blockIdx.z;   // 0: Q, 1: K
  const float* W = qk ? WK : WQ;
  const int m0 = mt * 64;
  const int tid = threadIdx.x;
  for (int idx = tid; idx < 64 * 32; idx += 256) {
    int i = idx >> 5, d = idx & 31;                    // read coalesced
    t[i][d] = W[((size_t)h * 1024 + m0 + i) * 32 + d];
  }
  __syncthreads();
  const int rowbase = qk * 1024 + h * 32;
  for (int idx = tid; idx < 32 * 64; idx += 256) {
    int d = idx >> 6, i = idx & 63;                    // write coalesced over m
    Wt[(size_t)(rowbase + d) * 1024 + m0 + i] = __float2bfloat16(t[i][d]);
  }
}

// ---- W_O (2048,1024) -> Wo_t[m*2048 + h] bf16 -----------------------------
__global__ void transpose_wo(const float* __restrict__ WO, bf16* __restrict__ Wt) {
  __shared__ float t[64][65];
  const int h0 = blockIdx.x * 64;   // 0..31 tiles
  const int m0 = blockIdx.y * 64;   // 0..15 tiles
  const int tid = threadIdx.x;
  for (int idx = tid; idx < 64 * 64; idx += 256) {
    int i = idx >> 6, j = idx & 63;                    // i: h, j: m (coalesced)
    t[i][j] = WO[(size_t)(h0 + i) * 1024 + m0 + j];
  }
  __syncthreads();
  for (int idx = tid; idx < 64 * 64; idx += 256) {
    int i = idx >> 6, j = idx & 63;                    // i: m, j: h (coalesced)
    Wt[(size_t)(m0 + i) * 2048 + h0 + j] = __float2bfloat16(t[j][i]);
  }
}

// ---- bf16 MFMA GEMM: C[M x ldc] = A[M x K] @ Bt[N x K]^T ------------------
// 128x128 tile per block (256 thr = 4 waves, 2x2 wave grid, 4x4 mfma/wave).
// A, Bt row stride == K. Dims must be multiples of 128 (they are).
__global__ __launch_bounds__(256) void gemm_bt(
    const bf16* __restrict__ A, const bf16* __restrict__ Bt, float* __restrict__ C,
    int K, int ldc) {
  __shared__ __align__(16) short As[128 * 32];
  __shared__ __align__(16) short Bs[128 * 32];
  const int tileM = blockIdx.y * 128, tileN = blockIdx.x * 128;
  const int tid = threadIdx.x, wave = tid >> 6, lane = tid & 63;
  const int wm = (wave >> 1) * 64, wn = (wave & 1) * 64;
  const int mrow = lane & 15, kq = lane >> 4;
  f32x4 acc[4][4] = {};

  for (int k0 = 0; k0 < K; k0 += 32) {
#pragma unroll
    for (int i = 0; i < 2; i++) {
      // chunk id c in [0,512): row = c>>2 (of 128), 16B piece (c&3) of the 64B row
      int c = (wave * 2 + i) * 64 + lane;
      int row = c >> 2, ko = (c & 3) * 8;
      const short* ga = (const short*)A + (size_t)(tileM + row) * K + k0 + ko;
      const short* gb = (const short*)Bt + (size_t)(tileN + row) * K + k0 + ko;
      // wave-uniform LDS base + lane*16 == linear chunk order
      __builtin_amdgcn_global_load_lds(AS1(ga), AS3(&As[(wave * 2 + i) * 512]), 16, 0, 0);
      __builtin_amdgcn_global_load_lds(AS1(gb), AS3(&Bs[(wave * 2 + i) * 512]), 16, 0, 0);
    }
    __syncthreads();
    bf16x8 af[4], bfr[4];
#pragma unroll
    for (int t = 0; t < 4; t++) {
      af[t]  = *(const bf16x8*)&As[(wm + t * 16 + mrow) * 32 + kq * 8];
      bfr[t] = *(const bf16x8*)&Bs[(wn + t * 16 + mrow) * 32 + kq * 8];
    }
#pragma unroll
    for (int i = 0; i < 4; i++)
#pragma unroll
      for (int j = 0; j < 4; j++)
        acc[i][j] = __builtin_amdgcn_mfma_f32_16x16x32_bf16(af[i], bfr[j], acc[i][j], 0, 0, 0);
    __syncthreads();
  }
  const int col = lane & 15, rq = lane >> 4;
#pragma unroll
  for (int i = 0; i < 4; i++)
#pragma unroll
    for (int j = 0; j < 4; j++)
#pragma unroll
      for (int r = 0; r < 4; r++) {
        int m = tileM + wm + i * 16 + rq * 4 + r;
        int n = tileN + wn + j * 16 + col;
        C[(size_t)m * ldc + n] = acc[i][j][r];
      }
}

// ---- rotary + bias on C1 cols 0..2047 (Q then K), all 32 dims per head ----
__global__ void rotary_bias(float* __restrict__ C1, const float* __restrict__ bQ,
                            const float* __restrict__ bK) {
  int idx = blockIdx.x * 256 + threadIdx.x;   // [0, 2048*1024)
  int row = idx >> 10;                        // token 0..2047
  int r = idx & 1023;
  int qk = r >> 9, h = (r >> 4) & 31, d = r & 15;
  int s = row & 1023;                         // position within batch
  const float* bias = qk ? bK : bQ;
  size_t base = (size_t)row * NC1 + qk * 1024 + h * 32 + d;
  float x0 = C1[base]      + bias[h * 32 + d];
  float x1 = C1[base + 16] + bias[h * 32 + d + 16];
  // freq = 10000^(d/16); angle = s / freq
  float inv_freq = exp2f(d * -0.8304820237218406f);   // -log2(10000)/16
  float ang = (float)s * inv_freq;
  float sv, cv;
  sincosf(ang, &sv, &cv);
  C1[base]      = x0 * cv - x1 * sv;
  C1[base + 16] = x1 * cv + x0 * sv;
}

// ---- attention: per (b, hq, 64-query tile); 4 lanes per query -------------
// mask: k <= q + 16; keys 0..1023 real (from C1), 1024..1039 virtual.
__global__ __launch_bounds__(256) void attn(
    const float* __restrict__ C1, const float* __restrict__ vk,
    const float* __restrict__ vv, const float* __restrict__ bV,
    bf16* __restrict__ Zb) {
  __shared__ float ks[64][32];
  __shared__ float vs[64][64];
  const int q0 = blockIdx.x * 64, hq = blockIdx.y, b = blockIdx.z;
  const int tid = threadIdx.x;
  const int qi = q0 + (tid >> 2), sub = tid & 3;
  float q8[8];
  {
    const float* qp = C1 + (size_t)(b * 1024 + qi) * NC1 + hq * 32 + sub * 8;
#pragma unroll
    for (int j = 0; j < 8; j++) q8[j] = qp[j];
  }
  float m = -1e30f, l = 0.f, z[16];
#pragma unroll
  for (int j = 0; j < 16; j++) z[j] = 0.f;

  const int kv_end = q0 + 80;   // last needed key is q0+63+16
  for (int kc = 0; kc < kv_end; kc += 64) {
    __syncthreads();
    for (int idx = tid; idx < 64 * 32; idx += 256) {
      int kl = idx >> 5, d = idx & 31, kg = kc + kl;
      float v;
      if (kg < 1024)      v = C1[(size_t)(b * 1024 + kg) * NC1 + 1024 + hq * 32 + d];
      else if (kg < 1040) v = vk[(size_t)(kg - 1024) * 1024 + hq * 32 + d];
      else                v = 0.f;
      ks[kl][d] = v;
    }
    for (int idx = tid; idx < 64 * 64; idx += 256) {
      int kl = idx >> 6, r2 = idx & 63, kg = kc + kl;
      float v;
      if (kg < 1024)      v = C1[(size_t)(b * 1024 + kg) * NC1 + 2048 + hq * 64 + r2] + bV[hq * 64 + r2];
      else if (kg < 1040) v = vv[(size_t)(kg - 1024) * 2048 + hq * 64 + r2];
      else                v = 0.f;
      vs[kl][r2] = v;
    }
    __syncthreads();
    int klim = qi + 17 - kc;                  // #valid keys in this chunk
    if (klim > 64) klim = 64;
    for (int kl = 0; kl < klim; kl++) {
      float sc = 0.f;
#pragma unroll
      for (int j = 0; j < 8; j++) sc += q8[j] * ks[kl][sub * 8 + j];
      sc += __shfl_xor(sc, 1);
      sc += __shfl_xor(sc, 2);
      sc *= INV_SCALE;
      float mn = fmaxf(m, sc);
      float al = __expf(m - mn);              // first iter: exp(-1e30)=0, z=0 anyway
      float pe = __expf(sc - mn);
      l = l * al + pe;
#pragma unroll
      for (int j = 0; j < 16; j++) z[j] = z[j] * al + pe * vs[kl][sub * 16 + j];
      m = mn;
    }
  }
  float inv = 1.f / l;                        // >=17 keys always -> l > 0
  bf16* zp = Zb + (size_t)(b * 1024 + qi) * 2048 + hq * 64 + sub * 16;
#pragma unroll
  for (int j = 0; j < 16; j++) zp[j] = __float2bfloat16(z[j] * inv);
}

// ---------------------------------------------------------------------------
extern "C" void kernel_launch(void* const* d_in, const int* in_sizes, int n_in,
                              void* d_out, int out_size, void* d_ws, size_t ws_size,
                              hipStream_t stream) {
  const float* resid = (const float*)d_in[0];
  const float* WQ = (const float*)d_in[1];
  const float* WK = (const float*)d_in[2];
  const float* WV = (const float*)d_in[3];
  const float* WO = (const float*)d_in[4];
  const float* bQ = (const float*)d_in[5];
  const float* bK = (const float*)d_in[6];
  const float* bV = (const float*)d_in[7];
  const float* vk = (const float*)d_in[8];
  const float* vv = (const float*)d_in[9];
  float* out = (float*)d_out;

  // workspace layout (56 MB total)
  char* ws = (char*)d_ws;
  bf16*  A_bf = (bf16*)(ws);                    // 2048x1024 bf16   (4 MB)
  bf16*  Wt   = (bf16*)(ws + (4u << 20));       // 4096x1024 bf16   (8 MB)
  bf16*  Wot  = (bf16*)(ws + (12u << 20));      // 1024x2048 bf16   (4 MB)
  bf16*  Zb   = (bf16*)(ws + (16u << 20));      // 2048x2048 bf16   (8 MB)
  float* C1   = (float*)(ws + (24u << 20));     // 2048x4096 f32    (32 MB)

  cvt_f32_bf16<<<2048, 256, 0, stream>>>(resid, A_bf, 2048 * 1024);
  cvt_f32_bf16<<<2048, 256, 0, stream>>>(WV, Wt + (size_t)2048 * 1024, 2048 * 1024);
  transpose_wqk<<<dim3(16, 32, 2), 256, 0, stream>>>(WQ, WK, Wt);
  transpose_wo<<<dim3(32, 16), 256, 0, stream>>>(WO, Wot);
  // C1 = A @ Wt^T : M=2048, N=4096, K=1024
  gemm_bt<<<dim3(32, 16), 256, 0, stream>>>(A_bf, Wt, C1, 1024, 4096);
  rotary_bias<<<8192, 256, 0, stream>>>(C1, bQ, bK);
  attn<<<dim3(16, 32, 2), 256, 0, stream>>>(C1, vk, vv, bV, Zb);
  // out = Zb @ Wot^T : M=2048, N=1024, K=2048
  gemm_bt<<<dim3(8, 16), 256, 0, stream>>>(Zb, Wot, out, 2048, 1024);
}

// Round 2
// 289.746 us; speedup vs baseline: 2.4351x; 2.4351x over previous
//
#include <hip/hip_runtime.h>
#include <hip/hip_bf16.h>
#include <math.h>

// ---------------------------------------------------------------------------
// LowRankSparseAttention on MI355X (gfx950)
//   1. cvt resid -> bf16 A; cvt W_V -> Wt rows 2048..4095; transpose W_Q/W_K/W_O
//   2. GEMM1 (bf16 MFMA 128x128): C1[2048x4096] f32 = A @ Wt^T  (Q|K|V)
//   3. rotary+bias: Q in-place (f32, C1), K -> Kb bf16 [b][1088][1024]
//      fill_k_virtual: Kb rows 1024..1039 = vk (no rotary/bias), 1040..1087 = 0
//      transpose_v: V+bV -> Vb bf16 [b][h][ch][tok(1088)] (virtual vv, pad 0)
//   4. attn_mfma: per-wave flash attention (MFMA QK^T and PV) -> Zb bf16
//   5. GEMM2: out[2048x1024] f32 = Zb @ Wo_t^T
// ---------------------------------------------------------------------------

typedef short bf16x8 __attribute__((ext_vector_type(8)));
typedef float f32x4 __attribute__((ext_vector_type(4)));
typedef __hip_bfloat16 bf16;

#define AS1(p) ((const __attribute__((address_space(1))) void*)(const void*)(p))
#define AS3(p) ((__attribute__((address_space(3))) void*)(void*)(p))

static constexpr float INV_SCALE = 0.17677669529663687f;  // 1/sqrt(32)

__device__ inline short f2bs(float x) {
  union { __hip_bfloat16 h; short s; } u;
  u.h = __float2bfloat16(x);
  return u.s;
}

// ---- f32 -> bf16 convert (n multiple of 4) --------------------------------
__global__ void cvt_f32_bf16(const float* __restrict__ src, bf16* __restrict__ dst, int n) {
  int i = (blockIdx.x * 256 + threadIdx.x) * 4;
  if (i < n) {
    float4 v = *(const float4*)(src + i);
    dst[i + 0] = __float2bfloat16(v.x);
    dst[i + 1] = __float2bfloat16(v.y);
    dst[i + 2] = __float2bfloat16(v.z);
    dst[i + 3] = __float2bfloat16(v.w);
  }
}

// ---- W_Q/W_K (32,1024,32) -> Wt[(qk*1024 + h*32 + d)*1024 + m] bf16 -------
__global__ void transpose_wqk(const float* __restrict__ WQ, const float* __restrict__ WK,
                              bf16* __restrict__ Wt) {
  __shared__ float t[64][33];
  const int mt = blockIdx.x;
  const int h  = blockIdx.y;
  const int qk = blockIdx.z;
  const float* W = qk ? WK : WQ;
  const int m0 = mt * 64;
  const int tid = threadIdx.x;
  for (int idx = tid; idx < 64 * 32; idx += 256) {
    int i = idx >> 5, d = idx & 31;
    t[i][d] = W[((size_t)h * 1024 + m0 + i) * 32 + d];
  }
  __syncthreads();
  const int rowbase = qk * 1024 + h * 32;
  for (int idx = tid; idx < 32 * 64; idx += 256) {
    int d = idx >> 6, i = idx & 63;
    Wt[(size_t)(rowbase + d) * 1024 + m0 + i] = __float2bfloat16(t[i][d]);
  }
}

// ---- W_O (2048,1024) -> Wo_t[m*2048 + h] bf16 -----------------------------
__global__ void transpose_wo(const float* __restrict__ WO, bf16* __restrict__ Wt) {
  __shared__ float t[64][65];
  const int h0 = blockIdx.x * 64;
  const int m0 = blockIdx.y * 64;
  const int tid = threadIdx.x;
  for (int idx = tid; idx < 64 * 64; idx += 256) {
    int i = idx >> 6, j = idx & 63;
    t[i][j] = WO[(size_t)(h0 + i) * 1024 + m0 + j];
  }
  __syncthreads();
  for (int idx = tid; idx < 64 * 64; idx += 256) {
    int i = idx >> 6, j = idx & 63;
    Wt[(size_t)(m0 + i) * 2048 + h0 + j] = __float2bfloat16(t[j][i]);
  }
}

// ---- bf16 MFMA GEMM: C[M x ldc] = A[M x K] @ Bt[N x K]^T ------------------
__global__ __launch_bounds__(256) void gemm_bt(
    const bf16* __restrict__ A, const bf16* __restrict__ Bt, float* __restrict__ C,
    int K, int ldc) {
  __shared__ __align__(16) short As[128 * 32];
  __shared__ __align__(16) short Bs[128 * 32];
  const int tileM = blockIdx.y * 128, tileN = blockIdx.x * 128;
  const int tid = threadIdx.x, wave = tid >> 6, lane = tid & 63;
  const int wm = (wave >> 1) * 64, wn = (wave & 1) * 64;
  const int mrow = lane & 15, kq = lane >> 4;
  f32x4 acc[4][4] = {};

  for (int k0 = 0; k0 < K; k0 += 32) {
#pragma unroll
    for (int i = 0; i < 2; i++) {
      int c = (wave * 2 + i) * 64 + lane;
      int row = c >> 2, ko = (c & 3) * 8;
      const short* ga = (const short*)A + (size_t)(tileM + row) * K + k0 + ko;
      const short* gb = (const short*)Bt + (size_t)(tileN + row) * K + k0 + ko;
      __builtin_amdgcn_global_load_lds(AS1(ga), AS3(&As[(wave * 2 + i) * 512]), 16, 0, 0);
      __builtin_amdgcn_global_load_lds(AS1(gb), AS3(&Bs[(wave * 2 + i) * 512]), 16, 0, 0);
    }
    __syncthreads();
    bf16x8 af[4], bfr[4];
#pragma unroll
    for (int t = 0; t < 4; t++) {
      af[t]  = *(const bf16x8*)&As[(wm + t * 16 + mrow) * 32 + kq * 8];
      bfr[t] = *(const bf16x8*)&Bs[(wn + t * 16 + mrow) * 32 + kq * 8];
    }
#pragma unroll
    for (int i = 0; i < 4; i++)
#pragma unroll
      for (int j = 0; j < 4; j++)
        acc[i][j] = __builtin_amdgcn_mfma_f32_16x16x32_bf16(af[i], bfr[j], acc[i][j], 0, 0, 0);
    __syncthreads();
  }
  const int col = lane & 15, rq = lane >> 4;
#pragma unroll
  for (int i = 0; i < 4; i++)
#pragma unroll
    for (int j = 0; j < 4; j++)
#pragma unroll
      for (int r = 0; r < 4; r++) {
        int m = tileM + wm + i * 16 + rq * 4 + r;
        int n = tileN + wn + j * 16 + col;
        C[(size_t)m * ldc + n] = acc[i][j][r];
      }
}

// ---- rotary + bias: Q back into C1 (f32); K -> Kb bf16 --------------------
__global__ void rotary_qk(float* __restrict__ C1, const float* __restrict__ bQ,
                          const float* __restrict__ bK, bf16* __restrict__ Kb) {
  int idx = blockIdx.x * 256 + threadIdx.x;   // [0, 2048*1024)
  int row = idx >> 10;
  int r = idx & 1023;
  int qk = r >> 9, h = (r >> 4) & 31, d = r & 15;
  int s = row & 1023, b = row >> 10;
  const float* bias = qk ? bK : bQ;
  size_t base = (size_t)row * 4096 + qk * 1024 + h * 32 + d;
  float x0 = C1[base]      + bias[h * 32 + d];
  float x1 = C1[base + 16] + bias[h * 32 + d + 16];
  float inv_freq = exp2f(d * -0.8304820237218406f);   // -log2(10000)/16
  float ang = (float)s * inv_freq;
  float sv, cv;
  sincosf(ang, &sv, &cv);
  float y0 = x0 * cv - x1 * sv;
  float y1 = x1 * cv + x0 * sv;
  if (qk == 0) {
    C1[base] = y0; C1[base + 16] = y1;
  } else {
    size_t kb = ((size_t)b * 1088 + s) * 1024 + h * 32 + d;
    Kb[kb]      = __float2bfloat16(y0);
    Kb[kb + 16] = __float2bfloat16(y1);
  }
}

// ---- Kb rows 1024..1087: virtual_k (16 rows) + zero pad -------------------
__global__ void fill_k_virtual(const float* __restrict__ vk, bf16* __restrict__ Kb) {
  int idx = blockIdx.x * 256 + threadIdx.x;   // [0, 2*64*1024)
  int b = idx >> 16, rem = idx & 65535;
  int j = rem >> 10, c = rem & 1023;
  float v = (j < 16) ? vk[j * 1024 + c] : 0.f;
  Kb[((size_t)b * 1088 + 1024 + j) * 1024 + c] = __float2bfloat16(v);
}

// ---- V + bV -> Vb[b][h][ch][tok] bf16 (tok 0..1023 real, 1024..1039 vv, pad 0)
__global__ void transpose_v(const float* __restrict__ C1, const float* __restrict__ vv,
                            const float* __restrict__ bV, bf16* __restrict__ Vb) {
  __shared__ float t[64][65];
  const int t0 = blockIdx.x * 64;      // 17 tiles cover 1088
  const int h = blockIdx.y, b = blockIdx.z;
  const int tid = threadIdx.x;
  for (int idx = tid; idx < 64 * 64; idx += 256) {
    int i = idx >> 6, j = idx & 63;    // i: tok-local, j: ch
    int tok = t0 + i;
    float v;
    if (tok < 1024)      v = C1[(size_t)(b * 1024 + tok) * 4096 + 2048 + h * 64 + j] + bV[h * 64 + j];
    else if (tok < 1040) v = vv[(size_t)(tok - 1024) * 2048 + h * 64 + j];
    else                 v = 0.f;
    t[i][j] = v;
  }
  __syncthreads();
  for (int idx = tid; idx < 64 * 64; idx += 256) {
    int i = idx >> 6, j = idx & 63;    // i: ch, j: tok-local
    Vb[((size_t)(b * 32 + h) * 64 + i) * 1088 + t0 + j] = __float2bfloat16(t[j][i]);
  }
}

// ---- MFMA flash attention -------------------------------------------------
// Block: 256 thr = 4 independent waves; wave handles 32 queries (2 m-blocks).
// Per 64-key chunk: S = Q@K^T (8 mfma), online softmax in C/D layout,
// P -> LDS (bf16, stride 72) -> A-frags, O += P@V (16 mfma, V B-frags direct
// 16B global loads from Vb[ch][tok]). No __syncthreads anywhere.
__global__ __launch_bounds__(256) void attn_mfma(
    const float* __restrict__ C1, const bf16* __restrict__ Kb,
    const bf16* __restrict__ Vb, bf16* __restrict__ Zb) {
  __shared__ __align__(16) short Pls[4][32 * 72];
  const int hq = blockIdx.y, b = blockIdx.z;
  const int wave = threadIdx.x >> 6, lane = threadIdx.x & 63;
  const int qw = blockIdx.x * 128 + wave * 32;     // wave's first query
  const int col = lane & 15, quad = lane >> 4;
  short* P = &Pls[wave][0];

  // Q A-frags (scale folded): lane holds Q[qw+mb*16+col][quad*8+j]
  bf16x8 qf[2];
#pragma unroll
  for (int mb = 0; mb < 2; mb++) {
    const float* qp = C1 + (size_t)(b * 1024 + qw + mb * 16 + col) * 4096 + hq * 32 + quad * 8;
#pragma unroll
    for (int j = 0; j < 8; j++) qf[mb][j] = f2bs(qp[j] * INV_SCALE);
  }

  f32x4 O[2][4] = {};
  float mrow[2][4], lrow[2][4];
#pragma unroll
  for (int mb = 0; mb < 2; mb++)
#pragma unroll
    for (int r = 0; r < 4; r++) { mrow[mb][r] = -1e30f; lrow[mb][r] = 0.f; }

  const int kend = (qw + 48 < 1040) ? qw + 48 : 1040;   // exclusive key bound
  for (int kc = 0; kc < kend; kc += 64) {
    // ---- S = Q @ K^T ----
    f32x4 S[2][4] = {};
#pragma unroll
    for (int nb = 0; nb < 4; nb++) {
      const bf16* kp = Kb + ((size_t)b * 1088 + kc + nb * 16 + col) * 1024 + hq * 32 + quad * 8;
      bf16x8 kf = *(const bf16x8*)kp;
#pragma unroll
      for (int mb = 0; mb < 2; mb++)
        S[mb][nb] = __builtin_amdgcn_mfma_f32_16x16x32_bf16(qf[mb], kf, S[mb][nb], 0, 0, 0);
    }
    // ---- mask: key kg visible iff kg <= qi + 16 ----
#pragma unroll
    for (int mb = 0; mb < 2; mb++)
#pragma unroll
      for (int nb = 0; nb < 4; nb++) {
        int kg = kc + nb * 16 + col;
#pragma unroll
        for (int r = 0; r < 4; r++) {
          int qi = qw + mb * 16 + quad * 4 + r;
          if (kg > qi + 16) S[mb][nb][r] = -1e30f;
        }
      }
    // ---- online softmax (C/D layout: col=lane&15, row=quad*4+r) ----
#pragma unroll
    for (int mb = 0; mb < 2; mb++) {
      float alpha[4];
#pragma unroll
      for (int r = 0; r < 4; r++) {
        float t0 = fmaxf(fmaxf(S[mb][0][r], S[mb][1][r]), fmaxf(S[mb][2][r], S[mb][3][r]));
        t0 = fmaxf(t0, __shfl_xor(t0, 1));
        t0 = fmaxf(t0, __shfl_xor(t0, 2));
        t0 = fmaxf(t0, __shfl_xor(t0, 4));
        t0 = fmaxf(t0, __shfl_xor(t0, 8));
        float mn = fmaxf(mrow[mb][r], t0);
        alpha[r] = __expf(mrow[mb][r] - mn);
        mrow[mb][r] = mn;
        float ps = 0.f;
#pragma unroll
        for (int nb = 0; nb < 4; nb++) {
          float p = __expf(S[mb][nb][r] - mn);
          S[mb][nb][r] = p;
          ps += p;
        }
        ps += __shfl_xor(ps, 1);
        ps += __shfl_xor(ps, 2);
        ps += __shfl_xor(ps, 4);
        ps += __shfl_xor(ps, 8);
        lrow[mb][r] = lrow[mb][r] * alpha[r] + ps;
      }
#pragma unroll
      for (int cb = 0; cb < 4; cb++)
#pragma unroll
        for (int r = 0; r < 4; r++) O[mb][cb][r] *= alpha[r];
      // P -> LDS bf16, row-major [q][k], stride 72 (2-way-conflict pad)
#pragma unroll
      for (int nb = 0; nb < 4; nb++)
#pragma unroll
        for (int r = 0; r < 4; r++)
          P[(mb * 16 + quad * 4 + r) * 72 + nb * 16 + col] = f2bs(S[mb][nb][r]);
    }
    asm volatile("s_waitcnt lgkmcnt(0)" ::: "memory");
    // ---- O += P @ V ----
#pragma unroll
    for (int ks = 0; ks < 2; ks++) {
      bf16x8 pf[2];
#pragma unroll
      for (int mb = 0; mb < 2; mb++)
        pf[mb] = *(const bf16x8*)&P[(mb * 16 + col) * 72 + ks * 32 + quad * 8];
#pragma unroll
      for (int cb = 0; cb < 4; cb++) {
        const bf16* vp = Vb + ((size_t)(b * 32 + hq) * 64 + cb * 16 + col) * 1088 + kc + ks * 32 + quad * 8;
        bf16x8 vf = *(const bf16x8*)vp;
#pragma unroll
        for (int mb = 0; mb < 2; mb++)
          O[mb][cb] = __builtin_amdgcn_mfma_f32_16x16x32_bf16(pf[mb], vf, O[mb][cb], 0, 0, 0);
      }
    }
  }
  // ---- epilogue: normalize, write Zb[b*1024+q][h*64+ch] ----
#pragma unroll
  for (int mb = 0; mb < 2; mb++)
#pragma unroll
    for (int r = 0; r < 4; r++) {
      float inv = 1.f / lrow[mb][r];
      int qi = qw + mb * 16 + quad * 4 + r;
      bf16* zp = Zb + (size_t)(b * 1024 + qi) * 2048 + hq * 64;
#pragma unroll
      for (int cb = 0; cb < 4; cb++)
        zp[cb * 16 + col] = __float2bfloat16(O[mb][cb][r] * inv);
    }
}

// ---------------------------------------------------------------------------
extern "C" void kernel_launch(void* const* d_in, const int* in_sizes, int n_in,
                              void* d_out, int out_size, void* d_ws, size_t ws_size,
                              hipStream_t stream) {
  const float* resid = (const float*)d_in[0];
  const float* WQ = (const float*)d_in[1];
  const float* WK = (const float*)d_in[2];
  const float* WV = (const float*)d_in[3];
  const float* WO = (const float*)d_in[4];
  const float* bQ = (const float*)d_in[5];
  const float* bK = (const float*)d_in[6];
  const float* bV = (const float*)d_in[7];
  const float* vk = (const float*)d_in[8];
  const float* vv = (const float*)d_in[9];
  float* out = (float*)d_out;

  // workspace layout (~57 MB; phase-1 A_bf/Wt region reused by Zb/Kb)
  char* ws = (char*)d_ws;
  bf16*  A_bf = (bf16*)(ws);                      // 0..4MB      (phase 1)
  bf16*  Wt   = (bf16*)(ws + 4194304);            // 4..12MB     (phase 1)
  bf16*  Zb   = (bf16*)(ws);                      // 0..8MB      (phase 3+)
  bf16*  Kb   = (bf16*)(ws + 8388608);            // 8..12.25MB  (phase 2+)
  bf16*  Wot  = (bf16*)(ws + 13107200);           // 12.5..16.5MB
  float* C1   = (float*)(ws + 17301504);          // 16.5..48.5MB
  bf16*  Vb   = (bf16*)(ws + 50855936);           // 48.5..57MB

  cvt_f32_bf16<<<2048, 256, 0, stream>>>(resid, A_bf, 2048 * 1024);
  cvt_f32_bf16<<<2048, 256, 0, stream>>>(WV, Wt + (size_t)2048 * 1024, 2048 * 1024);
  transpose_wqk<<<dim3(16, 32, 2), 256, 0, stream>>>(WQ, WK, Wt);
  transpose_wo<<<dim3(32, 16), 256, 0, stream>>>(WO, Wot);
  // C1 = A @ Wt^T : M=2048, N=4096, K=1024
  gemm_bt<<<dim3(32, 16), 256, 0, stream>>>(A_bf, Wt, C1, 1024, 4096);
  rotary_qk<<<8192, 256, 0, stream>>>(C1, bQ, bK, Kb);
  fill_k_virtual<<<512, 256, 0, stream>>>(vk, Kb);
  transpose_v<<<dim3(17, 32, 2), 256, 0, stream>>>(C1, vv, bV, Vb);
  attn_mfma<<<dim3(8, 32, 2), 256, 0, stream>>>(C1, Kb, Vb, Zb);
  // out = Zb @ Wot^T : M=2048, N=1024, K=2048
  gemm_bt<<<dim3(8, 16), 256, 0, stream>>>(Zb, Wot, out, 2048, 1024);
}

// Round 3
// 245.353 us; speedup vs baseline: 2.8757x; 1.1809x over previous
//
#include <hip/hip_runtime.h>
#include <hip/hip_bf16.h>
#include <math.h>

// ---------------------------------------------------------------------------
// LowRankSparseAttention on MI355X (gfx950)
//   1. cvt resid -> bf16 A; cvt W_V -> Wt rows 2048..4095; transpose W_Q/W_K/W_O
//   2. GEMM1 (bf16 MFMA 128x128): C1b[2048x4096] bf16 = A @ Wt^T  (Q|K|V)
//   3. rotary+bias: Q -> Qb bf16 (scale folded), K -> Kb bf16 [b][1088][1024]
//      fill_k_virtual: Kb rows 1024..1039 = vk, 1040..1087 = 0
//      transpose_v: V+bV -> Vb bf16 [b][h][ch][tok-permuted(1088)]
//   4. attn_mfma: per-wave flash attention, S^T/O^T form, no LDS -> Zb bf16
//   5. GEMM2 (64x128 tiles): out[2048x1024] f32 = Zb @ Wo_t^T
// ---------------------------------------------------------------------------

typedef short bf16x8 __attribute__((ext_vector_type(8)));
typedef short short4v __attribute__((ext_vector_type(4)));
typedef float f32x4 __attribute__((ext_vector_type(4)));
typedef __hip_bfloat16 bf16;

#define AS1(p) ((const __attribute__((address_space(1))) void*)(const void*)(p))
#define AS3(p) ((__attribute__((address_space(3))) void*)(void*)(p))

static constexpr float INV_SCALE = 0.17677669529663687f;  // 1/sqrt(32)

__device__ inline short f2bs(float x) {
  union { __hip_bfloat16 h; short s; } u;
  u.h = __float2bfloat16(x);
  return u.s;
}

// ---- f32 -> bf16 convert (n multiple of 4) --------------------------------
__global__ void cvt_f32_bf16(const float* __restrict__ src, bf16* __restrict__ dst, int n) {
  int i = (blockIdx.x * 256 + threadIdx.x) * 4;
  if (i < n) {
    float4 v = *(const float4*)(src + i);
    dst[i + 0] = __float2bfloat16(v.x);
    dst[i + 1] = __float2bfloat16(v.y);
    dst[i + 2] = __float2bfloat16(v.z);
    dst[i + 3] = __float2bfloat16(v.w);
  }
}

// ---- W_Q/W_K (32,1024,32) -> Wt[(qk*1024 + h*32 + d)*1024 + m] bf16 -------
__global__ void transpose_wqk(const float* __restrict__ WQ, const float* __restrict__ WK,
                              bf16* __restrict__ Wt) {
  __shared__ float t[64][33];
  const int mt = blockIdx.x;
  const int h  = blockIdx.y;
  const int qk = blockIdx.z;
  const float* W = qk ? WK : WQ;
  const int m0 = mt * 64;
  const int tid = threadIdx.x;
  for (int idx = tid; idx < 64 * 32; idx += 256) {
    int i = idx >> 5, d = idx & 31;
    t[i][d] = W[((size_t)h * 1024 + m0 + i) * 32 + d];
  }
  __syncthreads();
  const int rowbase = qk * 1024 + h * 32;
  for (int idx = tid; idx < 32 * 64; idx += 256) {
    int d = idx >> 6, i = idx & 63;
    Wt[(size_t)(rowbase + d) * 1024 + m0 + i] = __float2bfloat16(t[i][d]);
  }
}

// ---- W_O (2048,1024) -> Wo_t[m*2048 + h] bf16 -----------------------------
__global__ void transpose_wo(const float* __restrict__ WO, bf16* __restrict__ Wt) {
  __shared__ float t[64][65];
  const int h0 = blockIdx.x * 64;
  const int m0 = blockIdx.y * 64;
  const int tid = threadIdx.x;
  for (int idx = tid; idx < 64 * 64; idx += 256) {
    int i = idx >> 6, j = idx & 63;
    t[i][j] = WO[(size_t)(h0 + i) * 1024 + m0 + j];
  }
  __syncthreads();
  for (int idx = tid; idx < 64 * 64; idx += 256) {
    int i = idx >> 6, j = idx & 63;
    Wt[(size_t)(m0 + i) * 2048 + h0 + j] = __float2bfloat16(t[j][i]);
  }
}

// ---- bf16 MFMA GEMM 128x128: C[M x ldc] = A[M x K] @ Bt[N x K]^T ----------
__global__ __launch_bounds__(256) void gemm_bt(
    const bf16* __restrict__ A, const bf16* __restrict__ Bt, void* __restrict__ C,
    int K, int ldc, int obf) {
  __shared__ __align__(16) short As[128 * 32];
  __shared__ __align__(16) short Bs[128 * 32];
  const int tileM = blockIdx.y * 128, tileN = blockIdx.x * 128;
  const int tid = threadIdx.x, wave = tid >> 6, lane = tid & 63;
  const int wm = (wave >> 1) * 64, wn = (wave & 1) * 64;
  const int mrow = lane & 15, kq = lane >> 4;
  f32x4 acc[4][4] = {};

  for (int k0 = 0; k0 < K; k0 += 32) {
#pragma unroll
    for (int i = 0; i < 2; i++) {
      int c = (wave * 2 + i) * 64 + lane;
      int row = c >> 2, ko = (c & 3) * 8;
      const short* ga = (const short*)A + (size_t)(tileM + row) * K + k0 + ko;
      const short* gb = (const short*)Bt + (size_t)(tileN + row) * K + k0 + ko;
      __builtin_amdgcn_global_load_lds(AS1(ga), AS3(&As[(wave * 2 + i) * 512]), 16, 0, 0);
      __builtin_amdgcn_global_load_lds(AS1(gb), AS3(&Bs[(wave * 2 + i) * 512]), 16, 0, 0);
    }
    __syncthreads();
    bf16x8 af[4], bfr[4];
#pragma unroll
    for (int t = 0; t < 4; t++) {
      af[t]  = *(const bf16x8*)&As[(wm + t * 16 + mrow) * 32 + kq * 8];
      bfr[t] = *(const bf16x8*)&Bs[(wn + t * 16 + mrow) * 32 + kq * 8];
    }
#pragma unroll
    for (int i = 0; i < 4; i++)
#pragma unroll
      for (int j = 0; j < 4; j++)
        acc[i][j] = __builtin_amdgcn_mfma_f32_16x16x32_bf16(af[i], bfr[j], acc[i][j], 0, 0, 0);
    __syncthreads();
  }
  const int col = lane & 15, rq = lane >> 4;
#pragma unroll
  for (int i = 0; i < 4; i++)
#pragma unroll
    for (int j = 0; j < 4; j++)
#pragma unroll
      for (int r = 0; r < 4; r++) {
        int m = tileM + wm + i * 16 + rq * 4 + r;
        int n = tileN + wn + j * 16 + col;
        if (obf) ((bf16*)C)[(size_t)m * ldc + n] = __float2bfloat16(acc[i][j][r]);
        else     ((float*)C)[(size_t)m * ldc + n] = acc[i][j][r];
      }
}

// ---- bf16 MFMA GEMM 64x128 tile (more blocks for small-M GEMMs) -----------
__global__ __launch_bounds__(256) void gemm_bt64(
    const bf16* __restrict__ A, const bf16* __restrict__ Bt, void* __restrict__ C,
    int K, int ldc, int obf) {
  __shared__ __align__(16) short As[64 * 32];
  __shared__ __align__(16) short Bs[128 * 32];
  const int tileM = blockIdx.y * 64, tileN = blockIdx.x * 128;
  const int tid = threadIdx.x, wave = tid >> 6, lane = tid & 63;
  const int wm = (wave >> 1) * 32, wn = (wave & 1) * 64;
  const int mrow = lane & 15, kq = lane >> 4;
  f32x4 acc[2][4] = {};

  for (int k0 = 0; k0 < K; k0 += 32) {
    {
      int c = wave * 64 + lane;                       // A: 256 chunks
      int row = c >> 2, ko = (c & 3) * 8;
      const short* ga = (const short*)A + (size_t)(tileM + row) * K + k0 + ko;
      __builtin_amdgcn_global_load_lds(AS1(ga), AS3(&As[wave * 512]), 16, 0, 0);
    }
#pragma unroll
    for (int i = 0; i < 2; i++) {                     // B: 512 chunks
      int c = (wave * 2 + i) * 64 + lane;
      int row = c >> 2, ko = (c & 3) * 8;
      const short* gb = (const short*)Bt + (size_t)(tileN + row) * K + k0 + ko;
      __builtin_amdgcn_global_load_lds(AS1(gb), AS3(&Bs[(wave * 2 + i) * 512]), 16, 0, 0);
    }
    __syncthreads();
    bf16x8 af[2], bfr[4];
#pragma unroll
    for (int t = 0; t < 2; t++)
      af[t]  = *(const bf16x8*)&As[(wm + t * 16 + mrow) * 32 + kq * 8];
#pragma unroll
    for (int t = 0; t < 4; t++)
      bfr[t] = *(const bf16x8*)&Bs[(wn + t * 16 + mrow) * 32 + kq * 8];
#pragma unroll
    for (int i = 0; i < 2; i++)
#pragma unroll
      for (int j = 0; j < 4; j++)
        acc[i][j] = __builtin_amdgcn_mfma_f32_16x16x32_bf16(af[i], bfr[j], acc[i][j], 0, 0, 0);
    __syncthreads();
  }
  const int col = lane & 15, rq = lane >> 4;
#pragma unroll
  for (int i = 0; i < 2; i++)
#pragma unroll
    for (int j = 0; j < 4; j++)
#pragma unroll
      for (int r = 0; r < 4; r++) {
        int m = tileM + wm + i * 16 + rq * 4 + r;
        int n = tileN + wn + j * 16 + col;
        if (obf) ((bf16*)C)[(size_t)m * ldc + n] = __float2bfloat16(acc[i][j][r]);
        else     ((float*)C)[(size_t)m * ldc + n] = acc[i][j][r];
      }
}

// ---- rotary + bias: Q -> Qb bf16 (scale folded), K -> Kb bf16 -------------
__global__ void rotary_qk(const bf16* __restrict__ C1b, const float* __restrict__ bQ,
                          const float* __restrict__ bK, bf16* __restrict__ Qb,
                          bf16* __restrict__ Kb) {
  int idx = blockIdx.x * 256 + threadIdx.x;   // [0, 2048*1024)
  int row = idx >> 10;
  int r = idx & 1023;
  int qk = r >> 9, h = (r >> 4) & 31, d = r & 15;
  int s = row & 1023, b = row >> 10;
  const float* bias = qk ? bK : bQ;
  size_t base = (size_t)row * 4096 + qk * 1024 + h * 32 + d;
  float x0 = __bfloat162float(C1b[base])      + bias[h * 32 + d];
  float x1 = __bfloat162float(C1b[base + 16]) + bias[h * 32 + d + 16];
  float inv_freq = exp2f(d * -0.8304820237218406f);   // -log2(10000)/16
  float ang = (float)s * inv_freq;
  float sv, cv;
  sincosf(ang, &sv, &cv);
  float y0 = x0 * cv - x1 * sv;
  float y1 = x1 * cv + x0 * sv;
  if (qk == 0) {
    size_t qb = (size_t)row * 1024 + h * 32 + d;
    Qb[qb]      = __float2bfloat16(y0 * INV_SCALE);
    Qb[qb + 16] = __float2bfloat16(y1 * INV_SCALE);
  } else {
    size_t kb = ((size_t)b * 1088 + s) * 1024 + h * 32 + d;
    Kb[kb]      = __float2bfloat16(y0);
    Kb[kb + 16] = __float2bfloat16(y1);
  }
}

// ---- Kb rows 1024..1087: virtual_k (16 rows) + zero pad -------------------
__global__ void fill_k_virtual(const float* __restrict__ vk, bf16* __restrict__ Kb) {
  int idx = blockIdx.x * 256 + threadIdx.x;   // [0, 2*64*1024)
  int b = idx >> 16, rem = idx & 65535;
  int j = rem >> 10, c = rem & 1023;
  float v = (j < 16) ? vk[j * 1024 + c] : 0.f;
  Kb[((size_t)b * 1088 + 1024 + j) * 1024 + c] = __float2bfloat16(v);
}

// ---- V + bV -> Vb[b][h][ch][tok-PERMUTED] bf16 ----------------------------
// Within each 32-token group, storage position p holds source token
// u(p) = ((p&4)<<2) | ((p&24)>>1) | (p&3)  -- so that a 16B load at
// offset quad*8 yields exactly the keys matching the S^T C/D register order.
__global__ void transpose_v(const bf16* __restrict__ C1b, const float* __restrict__ vv,
                            const float* __restrict__ bV, bf16* __restrict__ Vb) {
  __shared__ float tile[64][65];
  const int t0 = blockIdx.x * 64;      // 17 tiles cover 1088
  const int h = blockIdx.y, b = blockIdx.z;
  const int tid = threadIdx.x;
  for (int idx = tid; idx < 64 * 64; idx += 256) {
    int i = idx >> 6, j = idx & 63;    // i: tok-local, j: ch
    int tok = t0 + i;
    float v;
    if (tok < 1024)      v = __bfloat162float(C1b[(size_t)(b * 1024 + tok) * 4096 + 2048 + h * 64 + j]) + bV[h * 64 + j];
    else if (tok < 1040) v = vv[(size_t)(tok - 1024) * 2048 + h * 64 + j];
    else                 v = 0.f;
    tile[i][j] = v;
  }
  __syncthreads();
  for (int idx = tid; idx < 64 * 64; idx += 256) {
    int i = idx >> 6, j = idx & 63;    // i: ch, j: out position
    int p = j & 31;
    int u = ((p & 4) << 2) | ((p & 24) >> 1) | (p & 3);
    int srcj = (j & 32) | u;
    Vb[((size_t)(b * 32 + h) * 64 + i) * 1088 + t0 + j] = __float2bfloat16(tile[srcj][i]);
  }
}

// ---- MFMA flash attention, transposed form, zero LDS ----------------------
// Wave = 16 queries (tile t, qw = 16t). S^T = K@Q^T so each lane owns one
// query column: m/l/alpha are lane scalars, softmax reduce = 2 shfls.
// P stays in registers: packed S^T C/D regs ARE the PV B-frag because V is
// stored with the matching permuted token order. O^T via mfma(A=V^T,B=P).
// Mirrored tile map {x,31-x,32+x,63-x} balances chunk counts per block.
__global__ __launch_bounds__(256) void attn_mfma(
    const bf16* __restrict__ Qb, const bf16* __restrict__ Kb,
    const bf16* __restrict__ Vb, bf16* __restrict__ Zb) {
  const int x = blockIdx.x, hq = blockIdx.y, b = blockIdx.z;
  const int wave = threadIdx.x >> 6, lane = threadIdx.x & 63;
  const int col = lane & 15, quad = lane >> 4;
  const int t = (wave == 0) ? x : (wave == 1) ? 31 - x : (wave == 2) ? 32 + x : 63 - x;
  const int qw = t * 16;

  const bf16x8 qf = *(const bf16x8*)((const short*)Qb +
      ((size_t)(b * 1024 + qw + col)) * 1024 + hq * 32 + quad * 8);
  const short* kbase = (const short*)Kb + (size_t)b * 1088 * 1024 + hq * 32 + quad * 8;
  const short* vbase = (const short*)Vb + ((size_t)(b * 32 + hq) * 64 + col) * 1088 + quad * 8;

  f32x4 O[4] = {};
  float m = -1e30f, l = 0.f;

  const int kend = (qw + 32 < 1040) ? qw + 32 : 1040;
  for (int kc = 0; kc < kend; kc += 64) {
    // ---- S^T = K @ Q^T : lane holds S^T[key=kc+mbk*16+quad*4+r][q=qw+col]
    f32x4 St[4] = {};
#pragma unroll
    for (int mbk = 0; mbk < 4; mbk++) {
      bf16x8 kf = *(const bf16x8*)(kbase + (size_t)(kc + mbk * 16 + col) * 1024);
      St[mbk] = __builtin_amdgcn_mfma_f32_16x16x32_bf16(kf, qf, St[mbk], 0, 0, 0);
    }
    // ---- mask (boundary chunks only; wave-uniform branch) ----
    if (kc + 63 > qw + 16) {
      int qv = qw + col + 16;
#pragma unroll
      for (int mbk = 0; mbk < 4; mbk++)
#pragma unroll
        for (int r = 0; r < 4; r++)
          if (kc + mbk * 16 + quad * 4 + r > qv) St[mbk][r] = -1e30f;
    }
    // ---- online softmax: in-lane 16 + shfl_xor(16,32) ----
    float cm0 = fmaxf(fmaxf(St[0][0], St[0][1]), fmaxf(St[0][2], St[0][3]));
    float cm1 = fmaxf(fmaxf(St[1][0], St[1][1]), fmaxf(St[1][2], St[1][3]));
    float cm2 = fmaxf(fmaxf(St[2][0], St[2][1]), fmaxf(St[2][2], St[2][3]));
    float cm3 = fmaxf(fmaxf(St[3][0], St[3][1]), fmaxf(St[3][2], St[3][3]));
    float cmax = fmaxf(fmaxf(cm0, cm1), fmaxf(cm2, cm3));
    cmax = fmaxf(cmax, __shfl_xor(cmax, 16));
    cmax = fmaxf(cmax, __shfl_xor(cmax, 32));
    float mn = fmaxf(m, cmax);
    float al = __expf(m - mn);
    m = mn;
    bf16x8 prs[2];
    float ps = 0.f;
#pragma unroll
    for (int mbk = 0; mbk < 4; mbk++)
#pragma unroll
      for (int r = 0; r < 4; r++) {
        float p = __expf(St[mbk][r] - mn);
        ps += p;
        prs[mbk >> 1][(mbk & 1) * 4 + r] = f2bs(p);
      }
    ps += __shfl_xor(ps, 16);
    ps += __shfl_xor(ps, 32);
    l = l * al + ps;
#pragma unroll
    for (int cb = 0; cb < 4; cb++)
#pragma unroll
      for (int r = 0; r < 4; r++) O[cb][r] *= al;
    // ---- O^T += V^T @ P (permuted contraction; P direct from regs) ----
#pragma unroll
    for (int ks = 0; ks < 2; ks++)
#pragma unroll
      for (int cb = 0; cb < 4; cb++) {
        bf16x8 vf = *(const bf16x8*)(vbase + (size_t)cb * 16 * 1088 + kc + ks * 32);
        O[cb] = __builtin_amdgcn_mfma_f32_16x16x32_bf16(vf, prs[ks], O[cb], 0, 0, 0);
      }
  }
  // ---- epilogue: lane owns query qw+col; O^T[ch=cb*16+quad*4+r][q] ----
  float inv = 1.f / l;
  short* zrow = (short*)Zb + ((size_t)(b * 1024 + qw + col)) * 2048 + hq * 64 + quad * 4;
#pragma unroll
  for (int cb = 0; cb < 4; cb++) {
    short4v s4;
#pragma unroll
    for (int r = 0; r < 4; r++) s4[r] = f2bs(O[cb][r] * inv);
    *(short4v*)(zrow + cb * 16) = s4;
  }
}

// ---------------------------------------------------------------------------
extern "C" void kernel_launch(void* const* d_in, const int* in_sizes, int n_in,
                              void* d_out, int out_size, void* d_ws, size_t ws_size,
                              hipStream_t stream) {
  const float* resid = (const float*)d_in[0];
  const float* WQ = (const float*)d_in[1];
  const float* WK = (const float*)d_in[2];
  const float* WV = (const float*)d_in[3];
  const float* WO = (const float*)d_in[4];
  const float* bQ = (const float*)d_in[5];
  const float* bK = (const float*)d_in[6];
  const float* bV = (const float*)d_in[7];
  const float* vk = (const float*)d_in[8];
  const float* vv = (const float*)d_in[9];
  float* out = (float*)d_out;

  // workspace layout (~45 MB), lifetime-overlapped:
  char* ws = (char*)d_ws;
  bf16* Wt   = (bf16*)(ws);                 // [0, 8M)     phases A-B (gemm1 in)
  bf16* Zb   = (bf16*)(ws);                 // [0, 8M)     phases D-E
  bf16* A_bf = (bf16*)(ws + 8388608);       // [8M, 12M)   phases A-B
  bf16* Qb   = (bf16*)(ws + 8388608);       // [8M, 12M)   phases C-D
  bf16* Kb   = (bf16*)(ws + 12582912);      // 4.46 MB
  bf16* Vb   = (bf16*)(ws + 17039360);      // 8.91 MB
  bf16* Wot  = (bf16*)(ws + 25952256);      // 4 MB
  bf16* C1b  = (bf16*)(ws + 30146560);      // 16 MB  (2048x4096 bf16)

  cvt_f32_bf16<<<2048, 256, 0, stream>>>(resid, A_bf, 2048 * 1024);
  cvt_f32_bf16<<<2048, 256, 0, stream>>>(WV, Wt + (size_t)2048 * 1024, 2048 * 1024);
  transpose_wqk<<<dim3(16, 32, 2), 256, 0, stream>>>(WQ, WK, Wt);
  transpose_wo<<<dim3(32, 16), 256, 0, stream>>>(WO, Wot);
  // C1b = A @ Wt^T : M=2048, N=4096, K=1024 (bf16 out)
  gemm_bt<<<dim3(32, 16), 256, 0, stream>>>(A_bf, Wt, C1b, 1024, 4096, 1);
  rotary_qk<<<8192, 256, 0, stream>>>(C1b, bQ, bK, Qb, Kb);
  fill_k_virtual<<<512, 256, 0, stream>>>(vk, Kb);
  transpose_v<<<dim3(17, 32, 2), 256, 0, stream>>>(C1b, vv, bV, Vb);
  attn_mfma<<<dim3(16, 32, 2), 256, 0, stream>>>(Qb, Kb, Vb, Zb);
  // out = Zb @ Wot^T : M=2048, N=1024, K=2048 (f32 out), 64-row tiles
  gemm_bt64<<<dim3(8, 32), 256, 0, stream>>>(Zb, Wot, out, 2048, 1024, 0);
}

// Round 4
// 229.024 us; speedup vs baseline: 3.0808x; 1.0713x over previous
//
#include <hip/hip_runtime.h>
#include <hip/hip_bf16.h>
#include <math.h>

// ---------------------------------------------------------------------------
// LowRankSparseAttention on MI355X (gfx950)
//   1. cvt resid -> A_bf; cvt W_V -> Wt rows 2048..4095; transpose W_Q/W_K/W_O
//   2. fill_kv_virtual: Kb rows 1024..1151 (vk + 0-pad), Vb toks 1024..1151
//   3. gemm1_fused (128x64 tiles, 1024 blocks): QKV proj with FUSED epilogue:
//        Q cols: +bQ, rotary, *1/sqrt(32) -> Qb bf16 [2048][1024]
//        K cols: +bK, rotary            -> Kb bf16 [b][1152][1024]
//        V cols: +bV, permuted transpose-> Vb bf16 [b*32+h][64][1152]
//   4. attn_mfma: per-wave flash attention, S^T/O^T form, 128-key chunks,
//      zero LDS, P never leaves registers -> Zb bf16
//   5. gemm2 (64x64 tiles, 512 blocks): out[2048x1024] f32 = Zb @ Wo_t^T
// ---------------------------------------------------------------------------

typedef short bf16x8 __attribute__((ext_vector_type(8)));
typedef short short4v __attribute__((ext_vector_type(4)));
typedef float f32x4 __attribute__((ext_vector_type(4)));
typedef __hip_bfloat16 bf16;

#define AS1(p) ((const __attribute__((address_space(1))) void*)(const void*)(p))
#define AS3(p) ((__attribute__((address_space(3))) void*)(void*)(p))

static constexpr float INV_SCALE = 0.17677669529663687f;  // 1/sqrt(32)

// fast RNE f32->bf16 (values guaranteed finite, no NaN path): 4 int ops
__device__ inline short rnd_bf16(float x) {
  unsigned u = __float_as_uint(x);
  return (short)((u + 0x7fffu + ((u >> 16) & 1u)) >> 16);
}

// ---- f32 -> bf16 convert (n multiple of 4) --------------------------------
__global__ void cvt_f32_bf16(const float* __restrict__ src, bf16* __restrict__ dst, int n) {
  int i = (blockIdx.x * 256 + threadIdx.x) * 4;
  if (i < n) {
    float4 v = *(const float4*)(src + i);
    short* d = (short*)dst + i;
    d[0] = rnd_bf16(v.x); d[1] = rnd_bf16(v.y);
    d[2] = rnd_bf16(v.z); d[3] = rnd_bf16(v.w);
  }
}

// ---- W_Q/W_K (32,1024,32) -> Wt[(qk*1024 + h*32 + d)*1024 + m] bf16 -------
__global__ void transpose_wqk(const float* __restrict__ WQ, const float* __restrict__ WK,
                              bf16* __restrict__ Wt) {
  __shared__ float t[64][33];
  const int mt = blockIdx.x, h = blockIdx.y, qk = blockIdx.z;
  const float* W = qk ? WK : WQ;
  const int m0 = mt * 64, tid = threadIdx.x;
  for (int idx = tid; idx < 64 * 32; idx += 256) {
    int i = idx >> 5, d = idx & 31;
    t[i][d] = W[((size_t)h * 1024 + m0 + i) * 32 + d];
  }
  __syncthreads();
  const int rowbase = qk * 1024 + h * 32;
  for (int idx = tid; idx < 32 * 64; idx += 256) {
    int d = idx >> 6, i = idx & 63;
    Wt[(size_t)(rowbase + d) * 1024 + m0 + i] = __float2bfloat16(t[i][d]);
  }
}

// ---- W_O (2048,1024) -> Wo_t[m*2048 + h] bf16 -----------------------------
__global__ void transpose_wo(const float* __restrict__ WO, bf16* __restrict__ Wt) {
  __shared__ float t[64][65];
  const int h0 = blockIdx.x * 64, m0 = blockIdx.y * 64, tid = threadIdx.x;
  for (int idx = tid; idx < 64 * 64; idx += 256) {
    int i = idx >> 6, j = idx & 63;
    t[i][j] = WO[(size_t)(h0 + i) * 1024 + m0 + j];
  }
  __syncthreads();
  for (int idx = tid; idx < 64 * 64; idx += 256) {
    int i = idx >> 6, j = idx & 63;
    Wt[(size_t)(m0 + i) * 2048 + h0 + j] = __float2bfloat16(t[j][i]);
  }
}

// ---- virtual rows: Kb rows 1024..1151, Vb positions 1024..1151 ------------
// Vb token permutation u(p) within 32-groups (see gemm1_fused epilogue).
__global__ void fill_kv_virtual(const float* __restrict__ vk, const float* __restrict__ vv,
                                bf16* __restrict__ Kb, bf16* __restrict__ Vb) {
  int idx = blockIdx.x * 256 + threadIdx.x;
  if (idx < 262144) {               // Kb: 2 b x 128 rows x 1024 cols
    int b = idx >> 17, rem = idx & 131071;
    int j = rem >> 10, c = rem & 1023;
    float v = (j < 16) ? vk[j * 1024 + c] : 0.f;
    Kb[((size_t)b * 1152 + 1024 + j) * 1024 + c] = __float2bfloat16(v);
  } else {                          // Vb: 2 b x 2048 ch x 128 positions
    int i2 = idx - 262144;
    int b = i2 >> 18, rem = i2 & 262143;
    int ch = rem >> 7, p = rem & 127;
    int pl = p & 31;
    int u = ((pl & 4) << 2) | ((pl & 24) >> 1) | (pl & 3);
    int tok = 1024 + (p & ~31) + u;
    float v = (tok < 1040) ? vv[(size_t)(tok - 1024) * 2048 + ch] : 0.f;
    int hv = ch >> 6, c = ch & 63;
    Vb[(((size_t)(b * 32 + hv)) * 64 + c) * 1152 + 1024 + p] = __float2bfloat16(v);
  }
}

// ---- GEMM1 + fused epilogue: 128(M) x 64(N) tiles, K=1024 -----------------
// C-fragment layout: m = wm+i*16+rq*4+r, n = wn+j*16+col. A 64-col tile is
// exactly one QK head (j=0: dims 0..15, j=1: dims 16..31) or one V head.
__global__ __launch_bounds__(256) void gemm1_fused(
    const bf16* __restrict__ A, const bf16* __restrict__ Bt,
    const float* __restrict__ bQ, const float* __restrict__ bK,
    const float* __restrict__ bV,
    bf16* __restrict__ Qb, bf16* __restrict__ Kb, bf16* __restrict__ Vb) {
  __shared__ __align__(16) short As[128 * 32];
  __shared__ __align__(16) short Bs[64 * 32];
  const int tileM = blockIdx.y * 128, tileN = blockIdx.x * 64;
  const int tid = threadIdx.x, wave = tid >> 6, lane = tid & 63;
  const int wm = (wave >> 1) * 64, wn = (wave & 1) * 32;
  const int mrow = lane & 15, kq = lane >> 4;
  f32x4 acc[4][2] = {};

  for (int k0 = 0; k0 < 1024; k0 += 32) {
#pragma unroll
    for (int i = 0; i < 2; i++) {                 // A: 512 chunks
      int c = (wave * 2 + i) * 64 + lane;
      int row = c >> 2, ko = (c & 3) * 8;
      const short* ga = (const short*)A + (size_t)(tileM + row) * 1024 + k0 + ko;
      __builtin_amdgcn_global_load_lds(AS1(ga), AS3(&As[(wave * 2 + i) * 512]), 16, 0, 0);
    }
    {                                             // B: 256 chunks
      int c = wave * 64 + lane;
      int row = c >> 2, ko = (c & 3) * 8;
      const short* gb = (const short*)Bt + (size_t)(tileN + row) * 1024 + k0 + ko;
      __builtin_amdgcn_global_load_lds(AS1(gb), AS3(&Bs[wave * 512]), 16, 0, 0);
    }
    __syncthreads();
    bf16x8 af[4], bfr[2];
#pragma unroll
    for (int t = 0; t < 4; t++) af[t] = *(const bf16x8*)&As[(wm + t * 16 + mrow) * 32 + kq * 8];
#pragma unroll
    for (int t = 0; t < 2; t++) bfr[t] = *(const bf16x8*)&Bs[(wn + t * 16 + mrow) * 32 + kq * 8];
#pragma unroll
    for (int i = 0; i < 4; i++)
#pragma unroll
      for (int j = 0; j < 2; j++)
        acc[i][j] = __builtin_amdgcn_mfma_f32_16x16x32_bf16(af[i], bfr[j], acc[i][j], 0, 0, 0);
    __syncthreads();
  }

  const int col = lane & 15, rq = lane >> 4;
  if (tileN < 2048) {
    // ---- Q or K head: bias + rotary (d = col, pair partner = acc[i][1]) ---
    const int qk = tileN >> 10;
    const int h = ((tileN & 1023) + wn) >> 5;
    const float* bias = qk ? bK : bQ;
    const float b0 = bias[h * 32 + col], b1 = bias[h * 32 + col + 16];
    const float invf = exp2f(col * -0.8304820237218406f);  // -log2(10000)/16
#pragma unroll
    for (int i = 0; i < 4; i++)
#pragma unroll
      for (int r = 0; r < 4; r++) {
        int m = tileM + wm + i * 16 + rq * 4 + r;
        int s = m & 1023, bb = m >> 10;
        float x0 = acc[i][0][r] + b0, x1 = acc[i][1][r] + b1;
        float sv, cv;
        __sincosf((float)s * invf, &sv, &cv);
        float y0 = x0 * cv - x1 * sv, y1 = x1 * cv + x0 * sv;
        if (qk == 0) {
          short* q = (short*)Qb + (size_t)m * 1024 + h * 32 + col;
          q[0]  = rnd_bf16(y0 * INV_SCALE);
          q[16] = rnd_bf16(y1 * INV_SCALE);
        } else {
          short* kp = (short*)Kb + ((size_t)bb * 1152 + s) * 1024 + h * 32 + col;
          kp[0]  = rnd_bf16(y0);
          kp[16] = rnd_bf16(y1);
        }
      }
  } else {
    // ---- V head: bias + permuted transpose into Vb[ch][tok] ---------------
    const int hv = (tileN - 2048) >> 6;
#pragma unroll
    for (int i = 0; i < 4; i++)
#pragma unroll
      for (int j = 0; j < 2; j++) {
        int c = wn + j * 16 + col;
        float bias = bV[hv * 64 + c];
        int m0 = tileM + wm + i * 16 + rq * 4;
        int s0 = m0 & 1023, bb = m0 >> 10;
        int u0 = s0 & 31;  // 4-aligned; permutation preserves low 2 bits
        int p0 = (u0 & 3) | ((u0 & 16) >> 2) | ((u0 & 8) << 1) | ((u0 & 4) << 1);
        short4v s4;
#pragma unroll
        for (int r = 0; r < 4; r++) s4[r] = rnd_bf16(acc[i][j][r] + bias);
        *(short4v*)((short*)Vb + (((size_t)(bb * 32 + hv)) * 64 + c) * 1152 + (s0 & ~31) + p0) = s4;
      }
  }
}

// ---- MFMA flash attention, transposed form, zero LDS, 128-key chunks ------
// Wave = 16 queries. S^T = K@Q^T: lane owns query column (m/l scalar, 2 shfl
// reduce). Packed S^T C/D regs ARE the PV B-frag (V stored token-permuted).
// Mirrored tile map {x,31-x,32+x,63-x} balances per-block chunk totals.
__global__ __launch_bounds__(256) void attn_mfma(
    const bf16* __restrict__ Qb, const bf16* __restrict__ Kb,
    const bf16* __restrict__ Vb, bf16* __restrict__ Zb) {
  const int x = blockIdx.x, hq = blockIdx.y, b = blockIdx.z;
  const int wave = threadIdx.x >> 6, lane = threadIdx.x & 63;
  const int col = lane & 15, quad = lane >> 4;
  const int t = (wave == 0) ? x : (wave == 1) ? 31 - x : (wave == 2) ? 32 + x : 63 - x;
  const int qw = t * 16;

  const bf16x8 qf = *(const bf16x8*)((const short*)Qb +
      ((size_t)(b * 1024 + qw + col)) * 1024 + hq * 32 + quad * 8);
  const short* kbase = (const short*)Kb + (size_t)b * 1152 * 1024 + hq * 32 + quad * 8;
  const short* vbase = (const short*)Vb + ((size_t)(b * 32 + hq) * 64 + col) * 1152 + quad * 8;

  f32x4 O[4] = {};
  float m = -1e30f, l = 0.f;

  const int kend = (qw + 32 < 1040) ? qw + 32 : 1040;
  for (int kc = 0; kc < kend; kc += 128) {
    // ---- S^T = K @ Q^T over 128 keys ----
    f32x4 St[8] = {};
#pragma unroll
    for (int mbk = 0; mbk < 8; mbk++) {
      bf16x8 kf = *(const bf16x8*)(kbase + (size_t)(kc + mbk * 16 + col) * 1024);
      St[mbk] = __builtin_amdgcn_mfma_f32_16x16x32_bf16(kf, qf, St[mbk], 0, 0, 0);
    }
    // ---- mask (boundary chunks only; wave-uniform branch) ----
    if (kc + 127 > qw + 16) {
      int qv = qw + col + 16;
#pragma unroll
      for (int mbk = 0; mbk < 8; mbk++)
#pragma unroll
        for (int r = 0; r < 4; r++)
          if (kc + mbk * 16 + quad * 4 + r > qv) St[mbk][r] = -1e30f;
    }
    // ---- online softmax: in-lane 32 + shfl_xor(16,32) ----
    float cmax = -1e30f;
#pragma unroll
    for (int mbk = 0; mbk < 8; mbk++) {
      float c01 = fmaxf(fmaxf(St[mbk][0], St[mbk][1]), fmaxf(St[mbk][2], St[mbk][3]));
      cmax = fmaxf(cmax, c01);
    }
    cmax = fmaxf(cmax, __shfl_xor(cmax, 16));
    cmax = fmaxf(cmax, __shfl_xor(cmax, 32));
    float mn = fmaxf(m, cmax);
    float al = __expf(m - mn);
    m = mn;
    bf16x8 prs[4];
    float ps = 0.f;
#pragma unroll
    for (int mbk = 0; mbk < 8; mbk++)
#pragma unroll
      for (int r = 0; r < 4; r++) {
        float p = __expf(St[mbk][r] - mn);
        ps += p;
        prs[mbk >> 1][(mbk & 1) * 4 + r] = rnd_bf16(p);
      }
    ps += __shfl_xor(ps, 16);
    ps += __shfl_xor(ps, 32);
    l = l * al + ps;
#pragma unroll
    for (int cb = 0; cb < 4; cb++)
#pragma unroll
      for (int r = 0; r < 4; r++) O[cb][r] *= al;
    // ---- O^T += V^T @ P (permuted contraction; P direct from regs) ----
#pragma unroll
    for (int ks = 0; ks < 4; ks++)
#pragma unroll
      for (int cb = 0; cb < 4; cb++) {
        bf16x8 vf = *(const bf16x8*)(vbase + (size_t)cb * 16 * 1152 + kc + ks * 32);
        O[cb] = __builtin_amdgcn_mfma_f32_16x16x32_bf16(vf, prs[ks], O[cb], 0, 0, 0);
      }
  }
  // ---- epilogue: lane owns query qw+col; O^T[ch=cb*16+quad*4+r][q] ----
  float inv = 1.f / l;
  short* zrow = (short*)Zb + ((size_t)(b * 1024 + qw + col)) * 2048 + hq * 64 + quad * 4;
#pragma unroll
  for (int cb = 0; cb < 4; cb++) {
    short4v s4;
#pragma unroll
    for (int r = 0; r < 4; r++) s4[r] = rnd_bf16(O[cb][r] * inv);
    *(short4v*)(zrow + cb * 16) = s4;
  }
}

// ---- GEMM2: 64x64 tiles, f32 out: out = Zb @ Wot^T ------------------------
__global__ __launch_bounds__(256) void gemm2_small(
    const bf16* __restrict__ A, const bf16* __restrict__ Bt, float* __restrict__ C,
    int K, int ldc) {
  __shared__ __align__(16) short As[64 * 32];
  __shared__ __align__(16) short Bs[64 * 32];
  const int tileM = blockIdx.y * 64, tileN = blockIdx.x * 64;
  const int tid = threadIdx.x, wave = tid >> 6, lane = tid & 63;
  const int wm = (wave >> 1) * 32, wn = (wave & 1) * 32;
  const int mrow = lane & 15, kq = lane >> 4;
  f32x4 acc[2][2] = {};

  for (int k0 = 0; k0 < K; k0 += 32) {
    {
      int c = wave * 64 + lane;
      int row = c >> 2, ko = (c & 3) * 8;
      const short* ga = (const short*)A + (size_t)(tileM + row) * K + k0 + ko;
      __builtin_amdgcn_global_load_lds(AS1(ga), AS3(&As[wave * 512]), 16, 0, 0);
    }
    {
      int c = wave * 64 + lane;
      int row = c >> 2, ko = (c & 3) * 8;
      const short* gb = (const short*)Bt + (size_t)(tileN + row) * K + k0 + ko;
      __builtin_amdgcn_global_load_lds(AS1(gb), AS3(&Bs[wave * 512]), 16, 0, 0);
    }
    __syncthreads();
    bf16x8 af[2], bfr[2];
#pragma unroll
    for (int t = 0; t < 2; t++) {
      af[t]  = *(const bf16x8*)&As[(wm + t * 16 + mrow) * 32 + kq * 8];
      bfr[t] = *(const bf16x8*)&Bs[(wn + t * 16 + mrow) * 32 + kq * 8];
    }
#pragma unroll
    for (int i = 0; i < 2; i++)
#pragma unroll
      for (int j = 0; j < 2; j++)
        acc[i][j] = __builtin_amdgcn_mfma_f32_16x16x32_bf16(af[i], bfr[j], acc[i][j], 0, 0, 0);
    __syncthreads();
  }
  const int col = lane & 15, rq = lane >> 4;
#pragma unroll
  for (int i = 0; i < 2; i++)
#pragma unroll
    for (int j = 0; j < 2; j++)
#pragma unroll
      for (int r = 0; r < 4; r++) {
        int mm = tileM + wm + i * 16 + rq * 4 + r;
        int nn = tileN + wn + j * 16 + col;
        C[(size_t)mm * ldc + nn] = acc[i][j][r];
      }
}

// ---------------------------------------------------------------------------
extern "C" void kernel_launch(void* const* d_in, const int* in_sizes, int n_in,
                              void* d_out, int out_size, void* d_ws, size_t ws_size,
                              hipStream_t stream) {
  const float* resid = (const float*)d_in[0];
  const float* WQ = (const float*)d_in[1];
  const float* WK = (const float*)d_in[2];
  const float* WV = (const float*)d_in[3];
  const float* WO = (const float*)d_in[4];
  const float* bQ = (const float*)d_in[5];
  const float* bK = (const float*)d_in[6];
  const float* bV = (const float*)d_in[7];
  const float* vk = (const float*)d_in[8];
  const float* vv = (const float*)d_in[9];
  float* out = (float*)d_out;

  // workspace layout, no aliasing (41.5 MB):
  char* ws = (char*)d_ws;
  bf16* A_bf = (bf16*)(ws);                 // 4 MB   [2048][1024]
  bf16* Wt   = (bf16*)(ws + 4194304);       // 8 MB   [4096][1024]
  bf16* Wot  = (bf16*)(ws + 12582912);      // 4 MB   [1024][2048]
  bf16* Qb   = (bf16*)(ws + 16777216);      // 4 MB   [2048][1024] (scaled)
  bf16* Kb   = (bf16*)(ws + 20971520);      // 4.5 MB [b][1152][1024]
  bf16* Vb   = (bf16*)(ws + 25690112);      // 9 MB   [b*32+h][64][1152] permuted
  bf16* Zb   = (bf16*)(ws + 35127296);      // 8 MB   [2048][2048]

  cvt_f32_bf16<<<2048, 256, 0, stream>>>(resid, A_bf, 2048 * 1024);
  cvt_f32_bf16<<<2048, 256, 0, stream>>>(WV, Wt + (size_t)2048 * 1024, 2048 * 1024);
  transpose_wqk<<<dim3(16, 32, 2), 256, 0, stream>>>(WQ, WK, Wt);
  transpose_wo<<<dim3(32, 16), 256, 0, stream>>>(WO, Wot);
  fill_kv_virtual<<<3072, 256, 0, stream>>>(vk, vv, Kb, Vb);
  // QKV projection + fused rotary/bias/transpose epilogue
  gemm1_fused<<<dim3(64, 16), 256, 0, stream>>>(A_bf, Wt, bQ, bK, bV, Qb, Kb, Vb);
  attn_mfma<<<dim3(16, 32, 2), 256, 0, stream>>>(Qb, Kb, Vb, Zb);
  // out = Zb @ Wot^T : M=2048, N=1024, K=2048
  gemm2_small<<<dim3(16, 32), 256, 0, stream>>>(Zb, Wot, out, 2048, 1024);
}

// Round 5
// 194.315 us; speedup vs baseline: 3.6311x; 1.1786x over previous
//
#include <hip/hip_runtime.h>
#include <hip/hip_bf16.h>
#include <math.h>

// ---------------------------------------------------------------------------
// LowRankSparseAttention on MI355X (gfx950)
//   1. prep (one kernel): cvt resid->A_bf, cvt W_V->Wt rows 2048+, virtual
//      K/V fills, transpose W_Q/W_K->Wt, transpose W_O->Wot
//   2. gemm1_fused (128x64 tiles): QKV proj, fused epilogue:
//        Q: +bQ, rotary, /sqrt(32) -> Qb bf16 [(b,h)][1024][32]   (dense)
//        K: +bK, rotary            -> Kb bf16 [(b,h)][1152][32]   (dense)
//        V: +bV, permuted transpose-> Vb bf16 [(b,h)][64][1152]
//   3. attn_mfma: per-wave flash attn, S^T/O^T form, 64-key chunks, zero LDS,
//      XCD-swizzled grid (each XCD owns 8 (hq,b) pairs) -> Zb bf16
//   4. gemm2 (64x64 tiles): out[2048x1024] f32 = Zb @ Wot^T
// ---------------------------------------------------------------------------

typedef short bf16x8 __attribute__((ext_vector_type(8)));
typedef short short4v __attribute__((ext_vector_type(4)));
typedef float f32x4 __attribute__((ext_vector_type(4)));
typedef __hip_bfloat16 bf16;

#define AS1(p) ((const __attribute__((address_space(1))) void*)(const void*)(p))
#define AS3(p) ((__attribute__((address_space(3))) void*)(void*)(p))

static constexpr float INV_SCALE = 0.17677669529663687f;  // 1/sqrt(32)

// fast RNE f32->bf16 (finite values only): 4 int ops
__device__ inline short rnd_bf16(float x) {
  unsigned u = __float_as_uint(x);
  return (short)((u + 0x7fffu + ((u >> 16) & 1u)) >> 16);
}

// ---- merged preprocessing kernel ------------------------------------------
// blocks 0..2047: cvt resid -> A_bf        (f32->bf16, 4/thread)
// blocks 2048..4095: cvt W_V -> Wt+2048*1024
// blocks 4096..7167: virtual K rows + virtual V positions
// blocks 7168..8191: transpose W_Q/W_K -> Wt rows 0..2047
// blocks 8192..8703: transpose W_O -> Wot
__global__ __launch_bounds__(256) void prep(
    const float* __restrict__ resid, const float* __restrict__ WV,
    const float* __restrict__ WQ, const float* __restrict__ WK,
    const float* __restrict__ WO, const float* __restrict__ vk,
    const float* __restrict__ vv,
    bf16* __restrict__ A_bf, bf16* __restrict__ Wt, bf16* __restrict__ Wot,
    bf16* __restrict__ Kb, bf16* __restrict__ Vb) {
  __shared__ float t[64][65];
  const int blk = blockIdx.x, tid = threadIdx.x;
  if (blk < 4096) {
    const float* src = (blk < 2048) ? resid : WV;
    short* dst = (short*)((blk < 2048) ? A_bf : (Wt + (size_t)2048 * 1024));
    int i = ((blk & 2047) * 256 + tid) * 4;
    float4 v = *(const float4*)(src + i);
    dst[i + 0] = rnd_bf16(v.x); dst[i + 1] = rnd_bf16(v.y);
    dst[i + 2] = rnd_bf16(v.z); dst[i + 3] = rnd_bf16(v.w);
  } else if (blk < 7168) {
    int idx = (blk - 4096) * 256 + tid;
    if (idx < 262144) {              // Kb virtual: toks 1024..1151 per (b,h)
      int b = idx >> 17, rem = idx & 131071;
      int j = rem >> 10, c = rem & 1023;     // c = h*32+d
      int h = c >> 5, d = c & 31;
      float v = (j < 16) ? vk[j * 1024 + c] : 0.f;
      Kb[(((size_t)(b * 32 + h)) * 1152 + 1024 + j) * 32 + d] = __float2bfloat16(v);
    } else {                         // Vb virtual positions 1024..1151
      int i2 = idx - 262144;
      int b = i2 >> 18, rem = i2 & 262143;
      int ch = rem >> 7, p = rem & 127;
      int pl = p & 31;
      int u = ((pl & 4) << 2) | ((pl & 24) >> 1) | (pl & 3);
      int tok = 1024 + (p & ~31) + u;
      float v = (tok < 1040) ? vv[(size_t)(tok - 1024) * 2048 + ch] : 0.f;
      int hv = ch >> 6, c = ch & 63;
      Vb[(((size_t)(b * 32 + hv)) * 64 + c) * 1152 + 1024 + p] = __float2bfloat16(v);
    }
  } else if (blk < 8192) {
    int i = blk - 7168;
    int mt = i & 15, h = (i >> 4) & 31, qk = i >> 9;
    const float* W = qk ? WK : WQ;
    const int m0 = mt * 64;
    for (int idx = tid; idx < 64 * 32; idx += 256) {
      int ii = idx >> 5, d = idx & 31;
      t[ii][d] = W[((size_t)h * 1024 + m0 + ii) * 32 + d];
    }
    __syncthreads();
    const int rowbase = qk * 1024 + h * 32;
    for (int idx = tid; idx < 32 * 64; idx += 256) {
      int d = idx >> 6, ii = idx & 63;
      Wt[(size_t)(rowbase + d) * 1024 + m0 + ii] = __float2bfloat16(t[ii][d]);
    }
  } else {
    int i = blk - 8192;
    int h0 = (i & 31) * 64, m0 = (i >> 5) * 64;
    for (int idx = tid; idx < 64 * 64; idx += 256) {
      int ii = idx >> 6, j = idx & 63;
      t[ii][j] = WO[(size_t)(h0 + ii) * 1024 + m0 + j];
    }
    __syncthreads();
    for (int idx = tid; idx < 64 * 64; idx += 256) {
      int ii = idx >> 6, j = idx & 63;
      Wot[(size_t)(m0 + ii) * 2048 + h0 + j] = __float2bfloat16(t[j][ii]);
    }
  }
}

// ---- GEMM1 + fused epilogue: 128(M) x 64(N) tiles, K=1024 -----------------
// C-frag: m = tileM+wm+i*16+rq*4+r, n = tileN+wn+j*16+col. A 64-col tile is
// two QK half-heads (j=0: dims 0..15, j=1: 16..31) or one V head.
__global__ __launch_bounds__(256) void gemm1_fused(
    const bf16* __restrict__ A, const bf16* __restrict__ Bt,
    const float* __restrict__ bQ, const float* __restrict__ bK,
    const float* __restrict__ bV,
    bf16* __restrict__ Qb, bf16* __restrict__ Kb, bf16* __restrict__ Vb) {
  __shared__ __align__(16) short As[128 * 32];
  __shared__ __align__(16) short Bs[64 * 32];
  const int tileM = blockIdx.y * 128, tileN = blockIdx.x * 64;
  const int tid = threadIdx.x, wave = tid >> 6, lane = tid & 63;
  const int wm = (wave >> 1) * 64, wn = (wave & 1) * 32;
  const int mrow = lane & 15, kq = lane >> 4;
  f32x4 acc[4][2] = {};

  for (int k0 = 0; k0 < 1024; k0 += 32) {
#pragma unroll
    for (int i = 0; i < 2; i++) {                 // A: 512 chunks
      int c = (wave * 2 + i) * 64 + lane;
      int row = c >> 2, ko = (c & 3) * 8;
      const short* ga = (const short*)A + (size_t)(tileM + row) * 1024 + k0 + ko;
      __builtin_amdgcn_global_load_lds(AS1(ga), AS3(&As[(wave * 2 + i) * 512]), 16, 0, 0);
    }
    {                                             // B: 256 chunks
      int c = wave * 64 + lane;
      int row = c >> 2, ko = (c & 3) * 8;
      const short* gb = (const short*)Bt + (size_t)(tileN + row) * 1024 + k0 + ko;
      __builtin_amdgcn_global_load_lds(AS1(gb), AS3(&Bs[wave * 512]), 16, 0, 0);
    }
    __syncthreads();
    bf16x8 af[4], bfr[2];
#pragma unroll
    for (int t = 0; t < 4; t++) af[t] = *(const bf16x8*)&As[(wm + t * 16 + mrow) * 32 + kq * 8];
#pragma unroll
    for (int t = 0; t < 2; t++) bfr[t] = *(const bf16x8*)&Bs[(wn + t * 16 + mrow) * 32 + kq * 8];
#pragma unroll
    for (int i = 0; i < 4; i++)
#pragma unroll
      for (int j = 0; j < 2; j++)
        acc[i][j] = __builtin_amdgcn_mfma_f32_16x16x32_bf16(af[i], bfr[j], acc[i][j], 0, 0, 0);
    __syncthreads();
  }

  const int col = lane & 15, rq = lane >> 4;
  if (tileN < 2048) {
    // ---- Q or K half-head pair: bias + rotary (d = col) -------------------
    const int qk = tileN >> 10;
    const int h = ((tileN & 1023) + wn) >> 5;
    const float* bias = qk ? bK : bQ;
    const float b0 = bias[h * 32 + col], b1 = bias[h * 32 + col + 16];
    const float invf = exp2f(col * -0.8304820237218406f);  // -log2(10000)/16
#pragma unroll
    for (int i = 0; i < 4; i++)
#pragma unroll
      for (int r = 0; r < 4; r++) {
        int m = tileM + wm + i * 16 + rq * 4 + r;
        int s = m & 1023, bb = m >> 10;
        float x0 = acc[i][0][r] + b0, x1 = acc[i][1][r] + b1;
        float sv, cv;
        __sincosf((float)s * invf, &sv, &cv);
        float y0 = x0 * cv - x1 * sv, y1 = x1 * cv + x0 * sv;
        if (qk == 0) {
          short* q = (short*)Qb + (((size_t)(bb * 32 + h)) * 1024 + s) * 32 + col;
          q[0]  = rnd_bf16(y0 * INV_SCALE);
          q[16] = rnd_bf16(y1 * INV_SCALE);
        } else {
          short* kp = (short*)Kb + (((size_t)(bb * 32 + h)) * 1152 + s) * 32 + col;
          kp[0]  = rnd_bf16(y0);
          kp[16] = rnd_bf16(y1);
        }
      }
  } else {
    // ---- V head: bias + permuted transpose into Vb[ch][tok] ---------------
    const int hv = (tileN - 2048) >> 6;
#pragma unroll
    for (int i = 0; i < 4; i++)
#pragma unroll
      for (int j = 0; j < 2; j++) {
        int c = wn + j * 16 + col;
        float bias = bV[hv * 64 + c];
        int m0 = tileM + wm + i * 16 + rq * 4;
        int s0 = m0 & 1023, bb = m0 >> 10;
        int u0 = s0 & 31;  // 4-aligned; permutation preserves low 2 bits
        int p0 = (u0 & 3) | ((u0 & 16) >> 2) | ((u0 & 8) << 1) | ((u0 & 4) << 1);
        short4v s4;
#pragma unroll
        for (int r = 0; r < 4; r++) s4[r] = rnd_bf16(acc[i][j][r] + bias);
        *(short4v*)((short*)Vb + (((size_t)(bb * 32 + hv)) * 64 + c) * 1152 + (s0 & ~31) + p0) = s4;
      }
  }
}

// ---- MFMA flash attention, transposed form, zero LDS, 64-key chunks -------
// 1-D grid, XCD-swizzled: xcd = flat&7 owns 8 (hq,b) pairs entirely, so K/V/Q
// head-slices are fetched into each XCD L2 exactly once (~2.3 MB/XCD).
// Wave = 16 queries; S^T = K@Q^T (lane owns query col; m/l scalar, 2-shfl
// reduce); packed S^T C/D regs ARE the PV B-frag (V token-permuted).
__global__ __launch_bounds__(256) void attn_mfma(
    const bf16* __restrict__ Qb, const bf16* __restrict__ Kb,
    const bf16* __restrict__ Vb, bf16* __restrict__ Zb) {
  const int flat = blockIdx.x;
  const int xcd = flat & 7, j = flat >> 3;
  const int hqb = xcd * 8 + (j & 7);
  const int x = j >> 3;
  const int hq = hqb & 31, b = hqb >> 5;
  const int wave = threadIdx.x >> 6, lane = threadIdx.x & 63;
  const int col = lane & 15, quad = lane >> 4;
  const int t = (wave == 0) ? x : (wave == 1) ? 31 - x : (wave == 2) ? 32 + x : 63 - x;
  const int qw = t * 16;

  const bf16x8 qf = *(const bf16x8*)((const short*)Qb +
      (((size_t)(b * 32 + hq)) * 1024 + qw + col) * 32 + quad * 8);
  const short* kbase = (const short*)Kb + ((size_t)(b * 32 + hq)) * 1152 * 32 + quad * 8;
  const short* vbase = (const short*)Vb + (((size_t)(b * 32 + hq)) * 64 + col) * 1152 + quad * 8;

  f32x4 O[4] = {};
  float m = -1e30f, l = 0.f;

  const int kend = (qw + 32 < 1040) ? qw + 32 : 1040;
  for (int kc = 0; kc < kend; kc += 64) {
    // ---- S^T = K @ Q^T : lane holds S^T[key=kc+mbk*16+quad*4+r][q=qw+col]
    f32x4 St[4] = {};
#pragma unroll
    for (int mbk = 0; mbk < 4; mbk++) {
      bf16x8 kf = *(const bf16x8*)(kbase + (size_t)(kc + mbk * 16 + col) * 32);
      St[mbk] = __builtin_amdgcn_mfma_f32_16x16x32_bf16(kf, qf, St[mbk], 0, 0, 0);
    }
    // ---- mask (boundary chunks only; wave-uniform branch) ----
    if (kc + 63 > qw + 16) {
      int qv = qw + col + 16;
#pragma unroll
      for (int mbk = 0; mbk < 4; mbk++)
#pragma unroll
        for (int r = 0; r < 4; r++)
          if (kc + mbk * 16 + quad * 4 + r > qv) St[mbk][r] = -1e30f;
    }
    // ---- online softmax: in-lane 16 + shfl_xor(16,32) ----
    float cm0 = fmaxf(fmaxf(St[0][0], St[0][1]), fmaxf(St[0][2], St[0][3]));
    float cm1 = fmaxf(fmaxf(St[1][0], St[1][1]), fmaxf(St[1][2], St[1][3]));
    float cm2 = fmaxf(fmaxf(St[2][0], St[2][1]), fmaxf(St[2][2], St[2][3]));
    float cm3 = fmaxf(fmaxf(St[3][0], St[3][1]), fmaxf(St[3][2], St[3][3]));
    float cmax = fmaxf(fmaxf(cm0, cm1), fmaxf(cm2, cm3));
    cmax = fmaxf(cmax, __shfl_xor(cmax, 16));
    cmax = fmaxf(cmax, __shfl_xor(cmax, 32));
    float mn = fmaxf(m, cmax);
    float al = __expf(m - mn);
    m = mn;
    bf16x8 prs[2];
    float ps = 0.f;
#pragma unroll
    for (int mbk = 0; mbk < 4; mbk++)
#pragma unroll
      for (int r = 0; r < 4; r++) {
        float p = __expf(St[mbk][r] - mn);
        ps += p;
        prs[mbk >> 1][(mbk & 1) * 4 + r] = rnd_bf16(p);
      }
    ps += __shfl_xor(ps, 16);
    ps += __shfl_xor(ps, 32);
    l = l * al + ps;
#pragma unroll
    for (int cb = 0; cb < 4; cb++)
#pragma unroll
      for (int r = 0; r < 4; r++) O[cb][r] *= al;
    // ---- O^T += V^T @ P (permuted contraction; P direct from regs) ----
#pragma unroll
    for (int ks = 0; ks < 2; ks++)
#pragma unroll
      for (int cb = 0; cb < 4; cb++) {
        bf16x8 vf = *(const bf16x8*)(vbase + (size_t)cb * 16 * 1152 + kc + ks * 32);
        O[cb] = __builtin_amdgcn_mfma_f32_16x16x32_bf16(vf, prs[ks], O[cb], 0, 0, 0);
      }
  }
  // ---- epilogue: lane owns query qw+col; O^T[ch=cb*16+quad*4+r][q] ----
  float inv = 1.f / l;
  short* zrow = (short*)Zb + ((size_t)(b * 1024 + qw + col)) * 2048 + hq * 64 + quad * 4;
#pragma unroll
  for (int cb = 0; cb < 4; cb++) {
    short4v s4;
#pragma unroll
    for (int r = 0; r < 4; r++) s4[r] = rnd_bf16(O[cb][r] * inv);
    *(short4v*)(zrow + cb * 16) = s4;
  }
}

// ---- GEMM2: 64x64 tiles, f32 out: out = Zb @ Wot^T ------------------------
__global__ __launch_bounds__(256) void gemm2_small(
    const bf16* __restrict__ A, const bf16* __restrict__ Bt, float* __restrict__ C,
    int K, int ldc) {
  __shared__ __align__(16) short As[64 * 32];
  __shared__ __align__(16) short Bs[64 * 32];
  const int tileM = blockIdx.y * 64, tileN = blockIdx.x * 64;
  const int tid = threadIdx.x, wave = tid >> 6, lane = tid & 63;
  const int wm = (wave >> 1) * 32, wn = (wave & 1) * 32;
  const int mrow = lane & 15, kq = lane >> 4;
  f32x4 acc[2][2] = {};

  for (int k0 = 0; k0 < K; k0 += 32) {
    {
      int c = wave * 64 + lane;
      int row = c >> 2, ko = (c & 3) * 8;
      const short* ga = (const short*)A + (size_t)(tileM + row) * K + k0 + ko;
      __builtin_amdgcn_global_load_lds(AS1(ga), AS3(&As[wave * 512]), 16, 0, 0);
    }
    {
      int c = wave * 64 + lane;
      int row = c >> 2, ko = (c & 3) * 8;
      const short* gb = (const short*)Bt + (size_t)(tileN + row) * K + k0 + ko;
      __builtin_amdgcn_global_load_lds(AS1(gb), AS3(&Bs[wave * 512]), 16, 0, 0);
    }
    __syncthreads();
    bf16x8 af[2], bfr[2];
#pragma unroll
    for (int t = 0; t < 2; t++) {
      af[t]  = *(const bf16x8*)&As[(wm + t * 16 + mrow) * 32 + kq * 8];
      bfr[t] = *(const bf16x8*)&Bs[(wn + t * 16 + mrow) * 32 + kq * 8];
    }
#pragma unroll
    for (int i = 0; i < 2; i++)
#pragma unroll
      for (int j = 0; j < 2; j++)
        acc[i][j] = __builtin_amdgcn_mfma_f32_16x16x32_bf16(af[i], bfr[j], acc[i][j], 0, 0, 0);
    __syncthreads();
  }
  const int col = lane & 15, rq = lane >> 4;
#pragma unroll
  for (int i = 0; i < 2; i++)
#pragma unroll
    for (int j = 0; j < 2; j++)
#pragma unroll
      for (int r = 0; r < 4; r++) {
        int mm = tileM + wm + i * 16 + rq * 4 + r;
        int nn = tileN + wn + j * 16 + col;
        C[(size_t)mm * ldc + nn] = acc[i][j][r];
      }
}

// ---------------------------------------------------------------------------
extern "C" void kernel_launch(void* const* d_in, const int* in_sizes, int n_in,
                              void* d_out, int out_size, void* d_ws, size_t ws_size,
                              hipStream_t stream) {
  const float* resid = (const float*)d_in[0];
  const float* WQ = (const float*)d_in[1];
  const float* WK = (const float*)d_in[2];
  const float* WV = (const float*)d_in[3];
  const float* WO = (const float*)d_in[4];
  const float* bQ = (const float*)d_in[5];
  const float* bK = (const float*)d_in[6];
  const float* bV = (const float*)d_in[7];
  const float* vk = (const float*)d_in[8];
  const float* vv = (const float*)d_in[9];
  float* out = (float*)d_out;

  // workspace layout, no aliasing (~41.5 MB):
  char* ws = (char*)d_ws;
  bf16* A_bf = (bf16*)(ws);                 // 4 MB   [2048][1024]
  bf16* Wt   = (bf16*)(ws + 4194304);       // 8 MB   [4096][1024]
  bf16* Wot  = (bf16*)(ws + 12582912);      // 4 MB   [1024][2048]
  bf16* Qb   = (bf16*)(ws + 16777216);      // 4 MB   [(b,h)][1024][32] scaled
  bf16* Kb   = (bf16*)(ws + 20971520);      // 4.5 MB [(b,h)][1152][32]
  bf16* Vb   = (bf16*)(ws + 25690112);      // 9 MB   [(b,h)][64][1152] permuted
  bf16* Zb   = (bf16*)(ws + 35127296);      // 8 MB   [2048][2048]

  prep<<<8704, 256, 0, stream>>>(resid, WV, WQ, WK, WO, vk, vv, A_bf, Wt, Wot, Kb, Vb);
  // QKV projection + fused rotary/bias/transpose epilogue
  gemm1_fused<<<dim3(64, 16), 256, 0, stream>>>(A_bf, Wt, bQ, bK, bV, Qb, Kb, Vb);
  attn_mfma<<<1024, 256, 0, stream>>>(Qb, Kb, Vb, Zb);
  // out = Zb @ Wot^T : M=2048, N=1024, K=2048
  gemm2_small<<<dim3(16, 32), 256, 0, stream>>>(Zb, Wot, out, 2048, 1024);
}